// Round 5
// baseline (179.044 us; speedup 1.0000x reference)
//
#include <hip/hip_runtime.h>

// MultiAttention fused pipeline for MI355X (gfx950).
// B=1, C=64, H=W=64 (N=4096), NH=8, DK=64, D=512.

#define LOG2E 1.442695040888963f

typedef __attribute__((ext_vector_type(8))) short bf16x8;
typedef __attribute__((ext_vector_type(4))) float f32x4;
typedef __attribute__((ext_vector_type(2))) float f32x2;
typedef __attribute__((ext_vector_type(4))) int i32x4;
typedef __attribute__((ext_vector_type(2))) int i32x2;
typedef __attribute__((ext_vector_type(4))) ushort u16x4;

__device__ __forceinline__ ushort f2bf(float x){
  uint u = __float_as_uint(x);
  u += 0x7fffu + ((u >> 16) & 1u);   // round-to-nearest-even
  return (ushort)(u >> 16);
}
__device__ __forceinline__ float bf2f(ushort h){
  return __uint_as_float(((uint)h) << 16);
}
__device__ __forceinline__ float gelu_(float x){
  return 0.5f * x * (1.0f + erff(x * 0.70710678118654752f));
}
__device__ __forceinline__ float sigmoid_(float x){
  return 1.0f / (1.0f + __expf(-x));
}
__device__ __forceinline__ float exp2_(float x){
  float r; asm("v_exp_f32 %0, %1" : "=v"(r) : "v"(x)); return r;
}
__device__ __forceinline__ int cvtpk(float lo, float hi){
  int r; asm("v_cvt_pk_bf16_f32 %0, %1, %2" : "=v"(r) : "v"(lo), "v"(hi)); return r;
}
__device__ __forceinline__ bf16x8 packf8(const float* s){
  f32x4 x0 = *(const f32x4*)s;
  f32x4 x1 = *(const f32x4*)(s+4);
  union{ i32x4 i; bf16x8 v; } u;
  u.i[0]=cvtpk(x0[0],x0[1]); u.i[1]=cvtpk(x0[2],x0[3]);
  u.i[2]=cvtpk(x1[0],x1[1]); u.i[3]=cvtpk(x1[2],x1[3]);
  return u.v;
}

// ---------------- K0: weight prep (Wout, si_w1 -> bf16) --------------------
__global__ __launch_bounds__(256) void k_wprep(const float* __restrict__ Wout,
    const float* __restrict__ si_w1, ushort* __restrict__ Woutb,
    ushort* __restrict__ si_w1b){
  int i = blockIdx.x*256 + threadIdx.x;
  if (i < 32768){ Woutb[i] = f2bf(Wout[i]); return; }
  i -= 32768;
  if (i < 16384){ si_w1b[i] = f2bf(si_w1[i]); }
}

// ---------------- K2: QKV projection (MFMA) + cosine norm for q,k ----------
// grid (256, 3): 16 rows/block, z = 0:q 1:k 2:v. q gets scale*log2e folded in.
__global__ __launch_bounds__(256) void k_qkv(const float* __restrict__ xin,
    const float* __restrict__ Wq, const float* __restrict__ Wk,
    const float* __restrict__ Wv, const float* __restrict__ scale,
    ushort* __restrict__ q_bf, ushort* __restrict__ k_bf, ushort* __restrict__ vT){
  const int z = blockIdx.y;
  const int n0 = blockIdx.x * 16;
  const int lane = threadIdx.x & 63, w = threadIdx.x >> 6;
  const int l15 = lane & 15, g = lane >> 4;
  const int obase = w * 128;
  const float* W = (z==0) ? Wq : (z==1) ? Wk : Wv;
  const int n = n0 + l15;
  float xa[8], xc[8];
#pragma unroll
  for (int j=0;j<8;j++){
    xa[j] = xin[(8*g + j)*4096 + n];
    xc[j] = xin[(32 + 8*g + j)*4096 + n];
  }
  union{ i32x4 i; bf16x8 v; } ua, uc;
  ua.i[0]=cvtpk(xa[0],xa[1]); ua.i[1]=cvtpk(xa[2],xa[3]);
  ua.i[2]=cvtpk(xa[4],xa[5]); ua.i[3]=cvtpk(xa[6],xa[7]);
  uc.i[0]=cvtpk(xc[0],xc[1]); uc.i[1]=cvtpk(xc[2],xc[3]);
  uc.i[2]=cvtpk(xc[4],xc[5]); uc.i[3]=cvtpk(xc[6],xc[7]);
  bf16x8 a0 = ua.v, a1 = uc.v;
  f32x4 acc[8];
#pragma unroll
  for (int t=0;t<8;t++) acc[t] = (f32x4){0.f,0.f,0.f,0.f};
#pragma unroll
  for (int t=0;t<8;t++){
    const float* brow = W + (size_t)(obase + 16*t + l15)*64;
    bf16x8 b0 = packf8(brow + 8*g);
    bf16x8 b1 = packf8(brow + 32 + 8*g);
    acc[t] = __builtin_amdgcn_mfma_f32_16x16x32_bf16(a0, b0, acc[t], 0,0,0);
    acc[t] = __builtin_amdgcn_mfma_f32_16x16x32_bf16(a1, b1, acc[t], 0,0,0);
  }
  if (z < 2){
#pragma unroll
    for (int hh=0; hh<2; hh++){
      float sfac = (z==0) ? (scale[2*w+hh] * LOG2E) : 1.0f;
#pragma unroll
      for (int r=0;r<4;r++){
        float ss = 0.f;
#pragma unroll
        for (int tt=0;tt<4;tt++){ float v = acc[hh*4+tt][r]; ss += v*v; }
        ss += __shfl_xor(ss, 1); ss += __shfl_xor(ss, 2);
        ss += __shfl_xor(ss, 4); ss += __shfl_xor(ss, 8);
        float inv = sfac / fmaxf(sqrtf(ss), 1e-12f);
#pragma unroll
        for (int tt=0;tt<4;tt++) acc[hh*4+tt][r] *= inv;
      }
    }
    ushort* dst = (z==0) ? q_bf : k_bf;
#pragma unroll
    for (int t=0;t<8;t++){
      int col = obase + 16*t + l15;
#pragma unroll
      for (int r=0;r<4;r++)
        dst[(size_t)(n0 + 4*g + r)*512 + col] = f2bf(acc[t][r]);
    }
  } else {
#pragma unroll
    for (int t=0;t<8;t++){
      int col = obase + 16*t + l15;
      u16x4 vs;
#pragma unroll
      for (int r=0;r<4;r++) vs[r] = f2bf(acc[t][r]);
      *(u16x4*)(vT + (size_t)col*4096 + n0 + 4*g) = vs;
    }
  }
}

// ---------------- K3: flash attention, LDS-staged, 64q/wave, kv-split ------
// block = 256 thr (4 waves), each wave 64 q-rows -> block covers 256 q.
// grid = 16 qb * 8 h * S; (h,seg) combo in low bits -> pinned per XCD.
// Scores cosine-normalized -> no-max softmax -> kv-split partials pure sums.
__global__ __launch_bounds__(256) void k_attn(const ushort* __restrict__ q_bf,
    const ushort* __restrict__ k_bf, const ushort* __restrict__ vT,
    float* __restrict__ O_part, float* __restrict__ lsum_part, int log2S){
  __shared__ ushort Kt[2][4096];
  __shared__ ushort Vt[2][4096];
  const int S = 1 << log2S;
  const int lin = blockIdx.x;
  const int combo = lin & (8*S - 1);
  const int qb = lin >> (3 + log2S);
  const int h = combo >> log2S;
  const int seg = combo & (S - 1);
  const int kv0 = seg * (4096 >> log2S);
  const int iters = (4096 >> log2S) >> 6;
  const int tid = threadIdx.x;
  const int lane = tid & 63, w = tid >> 6;
  const int l15 = lane & 15, g = lane >> 4;

  // staging: thread -> (row = 16*wave + l, 16-col chunk cb); 32B each of K,V
  const int sl = tid & 15, scb = (tid >> 4) & 3;
  const int srow = (tid >> 6)*16 + sl;
  const ushort* gK = k_bf + (size_t)(kv0 + srow)*512 + h*64 + scb*16;
  const ushort* gV = vT + (size_t)(h*64 + srow)*4096 + kv0 + scb*16;
  const int wO0 = srow*64 + (((2*scb)   ^ (srow & 7)) << 3);
  const int wO1 = srow*64 + (((2*scb+1) ^ (srow & 7)) << 3);

  // Q fragments: 64 rows per wave (4 tiles of 16)
  const int qrow0 = qb*256 + w*64;
  bf16x8 qa[4][2];
#pragma unroll
  for (int tq=0;tq<4;tq++){
    const ushort* qrow = q_bf + (size_t)(qrow0 + tq*16 + l15)*512 + h*64;
    qa[tq][0] = *(const bf16x8*)(qrow + 8*g);
    qa[tq][1] = *(const bf16x8*)(qrow + 32 + 8*g);
  }
  f32x4 O[4][4];
#pragma unroll
  for (int tq=0;tq<4;tq++)
#pragma unroll
    for (int t=0;t<4;t++) O[tq][t] = (f32x4){0.f,0.f,0.f,0.f};
  float lsum[4] = {0.f,0.f,0.f,0.f};

  // stage tile 0
  {
    i32x4 a = *(const i32x4*)gK, b = *(const i32x4*)(gK+8);
    i32x4 c = *(const i32x4*)gV, d = *(const i32x4*)(gV+8);
    *(i32x4*)&Kt[0][wO0] = a; *(i32x4*)&Kt[0][wO1] = b;
    *(i32x4*)&Vt[0][wO0] = c; *(i32x4*)&Vt[0][wO1] = d;
  }
  int buf = 0;
  const int x7 = l15 & 7;
  const int g2 = g >> 1, gh = (g & 1) << 2;

  for (int it = 0; it < iters; ++it){
    __syncthreads();
    i32x4 nk0, nk1, nv0, nv1;
    const bool pf = (it + 1 < iters);
    if (pf){
      gK += 64*512; gV += 64;
      nk0 = *(const i32x4*)gK; nk1 = *(const i32x4*)(gK+8);
      nv0 = *(const i32x4*)gV; nv1 = *(const i32x4*)(gV+8);
    }
    const ushort* Kb = Kt[buf];
    const ushort* Vb = Vt[buf];
    // QK^T (S^T: row=key, col=q) -> exp2 -> pack PV A-frags in-register
    i32x4 PA[4][2];
#pragma unroll
    for (int s=0;s<4;s++){
      const int rr = 16*s + l15;
      bf16x8 kf0 = *(const bf16x8*)&Kb[rr*64 + ((g     ^ x7) << 3)];
      bf16x8 kf1 = *(const bf16x8*)&Kb[rr*64 + (((4+g) ^ x7) << 3)];
      const int sp = s >> 1, hi = (s & 1) << 1;
#pragma unroll
      for (int tq=0;tq<4;tq++){
        f32x4 st = (f32x4){0.f,0.f,0.f,0.f};
        st = __builtin_amdgcn_mfma_f32_16x16x32_bf16(kf0, qa[tq][0], st, 0,0,0);
        st = __builtin_amdgcn_mfma_f32_16x16x32_bf16(kf1, qa[tq][1], st, 0,0,0);
        float p0 = exp2_(st[0]), p1 = exp2_(st[1]);
        float p2 = exp2_(st[2]), p3 = exp2_(st[3]);
        lsum[tq] += (p0 + p1) + (p2 + p3);
        PA[tq][sp][hi]   = cvtpk(p0, p1);
        PA[tq][sp][hi+1] = cvtpk(p2, p3);
      }
    }
    // PV
#pragma unroll
    for (int t=0;t<4;t++){
      const int rr = 16*t + l15;
      union { bf16x8 v; i32x2 h2[2]; } u0, u1;
      u0.h2[0] = *(const i32x2*)&Vb[rr*64 + ((g2       ^ x7) << 3) + gh];
      u0.h2[1] = *(const i32x2*)&Vb[rr*64 + (((2 + g2) ^ x7) << 3) + gh];
      u1.h2[0] = *(const i32x2*)&Vb[rr*64 + (((4 + g2) ^ x7) << 3) + gh];
      u1.h2[1] = *(const i32x2*)&Vb[rr*64 + (((6 + g2) ^ x7) << 3) + gh];
#pragma unroll
      for (int tq=0;tq<4;tq++){
        union { i32x4 i; bf16x8 v; } a0, a1;
        a0.i = PA[tq][0]; a1.i = PA[tq][1];
        O[tq][t] = __builtin_amdgcn_mfma_f32_16x16x32_bf16(a0.v, u0.v, O[tq][t], 0,0,0);
        O[tq][t] = __builtin_amdgcn_mfma_f32_16x16x32_bf16(a1.v, u1.v, O[tq][t], 0,0,0);
      }
    }
    if (pf){
      ushort* Kn = Kt[buf^1];
      ushort* Vn = Vt[buf^1];
      *(i32x4*)&Kn[wO0] = nk0; *(i32x4*)&Kn[wO1] = nk1;
      *(i32x4*)&Vn[wO0] = nv0; *(i32x4*)&Vn[wO1] = nv1;
    }
    buf ^= 1;
  }
  // partial softmax denominators (sum over g-groups; q = l15 col labeling)
#pragma unroll
  for (int tq=0;tq<4;tq++){
    float ls = lsum[tq];
    ls += __shfl_xor(ls, 16); ls += __shfl_xor(ls, 32);
    if (g == 0)
      lsum_part[((size_t)seg*8 + h)*4096 + qrow0 + tq*16 + l15] = ls;
  }
  float* Op = O_part + (size_t)seg*4096*512;
#pragma unroll
  for (int tq=0;tq<4;tq++)
#pragma unroll
    for (int t=0;t<4;t++)
#pragma unroll
      for (int r=0;r<4;r++)
        Op[(size_t)(qrow0 + tq*16 + 4*g + r)*512 + h*64 + 16*t + l15] = O[tq][t][r];
}

// ---------------- K3b: combine kv-split partials -> att_bf + pooled --------
__global__ __launch_bounds__(256) void k_comb(const float* __restrict__ O_part,
    const float* __restrict__ lsum_part, ushort* __restrict__ att_bf,
    float* __restrict__ pooled, int S){
  __shared__ float Linv[16][8];
  const int qbase = blockIdx.x * 16;
  const int tid = threadIdx.x;
  if (tid < 128){
    int q = tid >> 3, h = tid & 7;
    float L = 0.f;
    for (int s=0;s<S;s++) L += lsum_part[((size_t)s*8 + h)*4096 + qbase + q];
    Linv[q][h] = 1.0f / L;
  }
  __syncthreads();
  const int d2 = tid*2;
  const int h = d2 >> 6;
  float pool0 = 0.f, pool1 = 0.f;
  for (int q=0;q<16;q++){
    size_t idx = (size_t)(qbase + q)*512 + d2;
    float o0 = 0.f, o1 = 0.f;
    for (int s=0;s<S;s++){
      f32x2 ov = *(const f32x2*)(O_part + (size_t)s*4096*512 + idx);
      o0 += ov[0]; o1 += ov[1];
    }
    float li = Linv[q][h];
    o0 *= li; o1 *= li;
    uint pk = (uint)f2bf(o0) | ((uint)f2bf(o1) << 16);
    *(uint*)(att_bf + idx) = pk;
    pool0 += o0; pool1 += o1;
  }
  atomicAdd(&pooled[d2], pool0);
  atomicAdd(&pooled[d2+1], pool1);
}

// ---------------- K4: depthwise 3x3 + bias + BN + GELU (bf16 in/out) -------
__global__ __launch_bounds__(256) void k_conv(const ushort* __restrict__ vT,
    const float* __restrict__ dw_w, const float* __restrict__ dw_b,
    const float* __restrict__ dw_g, const float* __restrict__ dw_bt,
    const float* __restrict__ dw_m, const float* __restrict__ dw_v,
    ushort* __restrict__ conv_x){
  __shared__ float tile[4096];
  const int d = blockIdx.x;
  const int tid = threadIdx.x;
  const ushort* src = vT + (size_t)d*4096;
  {
    bf16x8 a = *(const bf16x8*)(src + tid*16);
    bf16x8 b = *(const bf16x8*)(src + tid*16 + 8);
#pragma unroll
    for (int j=0;j<8;j++){
      tile[tid*16 + j]     = bf2f((ushort)a[j]);
      tile[tid*16 + 8 + j] = bf2f((ushort)b[j]);
    }
  }
  __syncthreads();
  float wv[9];
#pragma unroll
  for (int i=0;i<9;i++) wv[i] = dw_w[d*9+i];
  const float bias = dw_b[d];
  const float bnsc = dw_g[d] * rsqrtf(dw_v[d] + 1e-5f);
  const float bnb  = dw_bt[d] - dw_m[d]*bnsc;
  ushort* dst = conv_x + (size_t)d*4096;
#pragma unroll 4
  for (int i=0;i<16;i++){
    int p = tid + 256*i;
    int y = p >> 6, x = p & 63;
    float acc = 0.f;
#pragma unroll
    for (int ky=0;ky<3;ky++){
      int yy = y + ky - 1;
      if (yy < 0 || yy > 63) continue;
#pragma unroll
      for (int kx=0;kx<3;kx++){
        int xx = x + kx - 1;
        if (xx < 0 || xx > 63) continue;
        acc += wv[ky*3+kx] * tile[yy*64 + xx];
      }
    }
    float cc = (acc + bias)*bnsc + bnb;
    dst[p] = f2bf(gelu_(cc));
  }
}

// ---------------- K4b: transpose conv_x [512][4096] -> conv_nd [4096][512] -
__global__ __launch_bounds__(256) void k_tr(const ushort* __restrict__ src,
    ushort* __restrict__ dst){
  __shared__ ushort tl[64*72];
  const int tid = threadIdx.x;
  const int n0 = (blockIdx.x & 63) * 64;
  const int d0 = (blockIdx.x >> 6) * 64;
  {
    const int r = tid & 63, ch = tid >> 6;   // r = d-row, ch = n-chunk
    union{ i32x4 q[2]; ushort e[16]; } u;
    const ushort* s = src + (size_t)(d0 + r)*4096 + n0 + ch*16;
    u.q[0] = *(const i32x4*)s;
    u.q[1] = *(const i32x4*)(s + 8);
#pragma unroll
    for (int j=0;j<16;j++) tl[(ch*16 + j)*72 + r] = u.e[j];
  }
  __syncthreads();
  {
    const int nr = tid & 63, dc = tid >> 6;
    i32x4 o0 = *(const i32x4*)&tl[nr*72 + dc*16];
    i32x4 o1 = *(const i32x4*)&tl[nr*72 + dc*16 + 8];
    ushort* dp = dst + (size_t)(n0 + nr)*512 + d0 + dc*16;
    *(i32x4*)dp = o0;
    *(i32x4*)(dp + 8) = o1;
  }
}

// ---------------- K5+K6: spatial (K-split MFMA, blocks 0..255) + channel ---
__global__ __launch_bounds__(256) void k_sc(const ushort* __restrict__ conv_nd,
    const ushort* __restrict__ si_w1b, const float* __restrict__ si_b1,
    const float* __restrict__ si_g, const float* __restrict__ si_bt,
    const float* __restrict__ si_m, const float* __restrict__ si_v,
    const float* __restrict__ si_w2, const float* __restrict__ si_b2,
    float* __restrict__ sig_sm,
    const float* __restrict__ pooled, const float* __restrict__ ci_w1,
    const float* __restrict__ ci_b1, const float* __restrict__ ci_w2,
    const float* __restrict__ ci_b2, float* __restrict__ sig_cm){
  const int tid = threadIdx.x;
  if (blockIdx.x == 256){
    __shared__ float pl[512];
    __shared__ float h1[128];
    pl[tid]       = pooled[tid]       * (1.0f/4096.0f);
    pl[tid + 256] = pooled[tid + 256] * (1.0f/4096.0f);
    __syncthreads();
    if (tid < 128){
      float acc = ci_b1[tid];
      const float* wr = ci_w1 + (size_t)tid*512;
#pragma unroll 4
      for (int c=0;c<512;c++) acc += wr[c]*pl[c];
      h1[tid] = gelu_(acc);
    }
    __syncthreads();
#pragma unroll
    for (int dd=0; dd<2; dd++){
      int d = tid + 256*dd;
      float acc = ci_b2[d];
      const float* wr = ci_w2 + (size_t)d*128;
#pragma unroll 4
      for (int e=0;e<128;e++) acc += wr[e]*h1[e];
      sig_cm[d] = sigmoid_(acc);
    }
    return;
  }
  // spatial: 16 n-rows per block, 4 waves split K (128 each), LDS-reduce.
  __shared__ f32x4 part2[4][2][64];
  const int lane = tid & 63, w = tid >> 6;
  const int l15 = lane & 15, g = lane >> 4;
  const int n0 = blockIdx.x * 16;
  const int arow = n0 + l15;
  f32x4 acc[2];
  acc[0] = (f32x4){0.f,0.f,0.f,0.f};
  acc[1] = (f32x4){0.f,0.f,0.f,0.f};
#pragma unroll
  for (int kk=0; kk<4; kk++){
    int k0 = w*128 + kk*32 + 8*g;
    bf16x8 a = *(const bf16x8*)(conv_nd + (size_t)arow*512 + k0);
#pragma unroll
    for (int t=0;t<2;t++){
      bf16x8 b = *(const bf16x8*)(si_w1b + (size_t)(16*t + l15)*512 + k0);
      acc[t] = __builtin_amdgcn_mfma_f32_16x16x32_bf16(a, b, acc[t], 0,0,0);
    }
  }
  part2[w][0][lane] = acc[0];
  part2[w][1][lane] = acc[1];
  __syncthreads();
  if (w == 0){
#pragma unroll
    for (int t=0;t<2;t++){
      f32x4 s4 = part2[0][t][lane];
#pragma unroll
      for (int ww=1;ww<4;ww++) s4 = s4 + part2[ww][t][lane];
      acc[t] = s4;
    }
    float rowv[4] = {0.f,0.f,0.f,0.f};
#pragma unroll
    for (int t=0;t<2;t++){
      int e = 16*t + l15;
      float s = si_g[e] * rsqrtf(si_v[e] + 1e-5f);
      float b1 = si_b1[e] - si_m[e];
      float bt = si_bt[e];
      float w2e = si_w2[e];
#pragma unroll
      for (int r=0;r<4;r++){
        float v = (acc[t][r] + b1)*s + bt;
        rowv[r] += w2e * gelu_(v);
      }
    }
    float sb2 = si_b2[0];
#pragma unroll
    for (int r=0;r<4;r++){
      float v = rowv[r];
      v += __shfl_xor(v,1); v += __shfl_xor(v,2);
      v += __shfl_xor(v,4); v += __shfl_xor(v,8);
      if (l15 == 0)
        sig_sm[n0 + 4*g + r] = sigmoid_(v + sb2);
    }
  }
}

// ---------------- K8: positional-embed branch, strip-split (256 blocks) ----
// block = (channel, 16-row strip). dw3x3 -> gelu -> dw3x3 with halo rows.
__global__ __launch_bounds__(256) void k_pe(const float* __restrict__ xin,
    const float* __restrict__ pe_w1, const float* __restrict__ pe_w2,
    float* __restrict__ embed){
  __shared__ float t0[20*64];
  __shared__ float t1[18*64];
  const int c = blockIdx.x >> 2;
  const int r0 = (blockIdx.x & 3) * 16;
  const int tid = threadIdx.x;
  const float* src = xin + (size_t)c*4096;
#pragma unroll
  for (int i=0;i<5;i++){
    int idx = tid + 256*i;
    if (idx < 1280){
      int lr = idx >> 6, x = idx & 63;
      int gr = r0 - 2 + lr;
      t0[idx] = (gr >= 0 && gr < 64) ? src[gr*64 + x] : 0.f;
    }
  }
  __syncthreads();
  float w1[9], w2[9];
#pragma unroll
  for (int i=0;i<9;i++){ w1[i] = pe_w1[c*9+i]; w2[i] = pe_w2[c*9+i]; }
#pragma unroll
  for (int i=0;i<5;i++){
    int idx = tid + 256*i;
    if (idx < 1152){
      int lr = idx >> 6, x = idx & 63;
      int gr = r0 - 1 + lr;
      float acc = 0.f;
      if (gr >= 0 && gr < 64){
#pragma unroll
        for (int ky=0;ky<3;ky++){
          int gy = gr + ky - 1;
          if (gy < 0 || gy > 63) continue;
#pragma unroll
          for (int kx=0;kx<3;kx++){
            int xx = x + kx - 1;
            if (xx < 0 || xx > 63) continue;
            acc += w1[ky*3+kx] * t0[(lr + ky)*64 + xx];  // lr+ky-1 +1 halo shift
          }
        }
        acc = gelu_(acc);
      }
      t1[idx] = acc;
    }
  }
  __syncthreads();
  float* dst = embed + (size_t)c*4096;
#pragma unroll
  for (int i=0;i<4;i++){
    int idx = tid + 256*i;
    int lr = idx >> 6, x = idx & 63;
    int gr = r0 + lr;
    float acc = 0.f;
#pragma unroll
    for (int ky=0;ky<3;ky++){
      int gy = gr + ky - 1;
      if (gy < 0 || gy > 63) continue;
#pragma unroll
      for (int kx=0;kx<3;kx++){
        int xx = x + kx - 1;
        if (xx < 0 || xx > 63) continue;
        acc += w2[ky*3+kx] * t1[(lr + ky)*64 + xx];      // t1 local row gr-1 -> lr+ky-1+... shift
      }
    }
    dst[gr*64 + x] = acc;
  }
}

// ---------------- K7: gate fuse + output GEMM (K-split 4 waves) + embed ----
// grid 256, block 256: 16 rows/block; wave w handles K-chunk [w*128,(w+1)*128).
__global__ __launch_bounds__(256) void k_final(const ushort* __restrict__ att_bf,
    const ushort* __restrict__ conv_nd, const float* __restrict__ sig_sm,
    const float* __restrict__ sig_cm, const ushort* __restrict__ Woutb,
    const float* __restrict__ bout, const float* __restrict__ embed,
    float* __restrict__ out){
  __shared__ f32x4 part[4][4][64];
  const int tid = threadIdx.x;
  const int lane = tid & 63, w = tid >> 6;
  const int l15 = lane & 15, g = lane >> 4;
  const int n0 = blockIdx.x * 16;
  const int rowA = n0 + l15;
  const float srow = sig_sm[rowA];
  f32x4 acc[4];
#pragma unroll
  for (int t=0;t<4;t++) acc[t] = (f32x4){0.f,0.f,0.f,0.f};
#pragma unroll
  for (int kk=0;kk<4;kk++){
    int k0 = w*128 + kk*32 + 8*g;
    bf16x8 at8 = *(const bf16x8*)(att_bf + (size_t)rowA*512 + k0);
    bf16x8 cn8 = *(const bf16x8*)(conv_nd + (size_t)rowA*512 + k0);
    bf16x8 af;
#pragma unroll
    for (int i=0;i<8;i++){
      int d = k0 + i;
      float zv = bf2f((ushort)at8[i]) * srow + bf2f((ushort)cn8[i]) * sig_cm[d];
      af[i] = (short)f2bf(zv);
    }
#pragma unroll
    for (int t=0;t<4;t++){
      bf16x8 bf8 = *(const bf16x8*)(Woutb + (size_t)(16*t+l15)*512 + k0);
      acc[t] = __builtin_amdgcn_mfma_f32_16x16x32_bf16(af, bf8, acc[t], 0,0,0);
    }
  }
#pragma unroll
  for (int t=0;t<4;t++) part[w][t][lane] = acc[t];
  __syncthreads();
  // wave w reduces output-column tile t=w: o = 16*w + l15
  {
    f32x4 s4 = part[0][w][lane];
#pragma unroll
    for (int ww=1;ww<4;ww++) s4 = s4 + part[ww][w][lane];
    int o = 16*w + l15;
    float bo = bout[o];
#pragma unroll
    for (int r=0;r<4;r++){
      int row = n0 + 4*g + r;
      size_t idx = (size_t)row*64 + o;
      out[idx] = s4[r] + bo + embed[idx];
    }
  }
}

extern "C" void kernel_launch(void* const* d_in, const int* in_sizes, int n_in,
                              void* d_out, int out_size, void* d_ws, size_t ws_size,
                              hipStream_t stream){
  (void)in_sizes; (void)n_in; (void)out_size;
  const float* x_in  = (const float*)d_in[0];
  const float* Wq    = (const float*)d_in[1];
  const float* Wk    = (const float*)d_in[2];
  const float* Wv    = (const float*)d_in[3];
  const float* scale = (const float*)d_in[4];
  const float* Wout  = (const float*)d_in[5];
  const float* bout  = (const float*)d_in[6];
  const float* dw_w  = (const float*)d_in[7];
  const float* dw_b  = (const float*)d_in[8];
  const float* dw_g  = (const float*)d_in[9];
  const float* dw_bt = (const float*)d_in[10];
  const float* dw_m  = (const float*)d_in[11];
  const float* dw_v  = (const float*)d_in[12];
  const float* ci_w1 = (const float*)d_in[13];
  const float* ci_b1 = (const float*)d_in[14];
  const float* ci_w2 = (const float*)d_in[15];
  const float* ci_b2 = (const float*)d_in[16];
  const float* si_w1 = (const float*)d_in[17];
  const float* si_b1 = (const float*)d_in[18];
  const float* si_g  = (const float*)d_in[19];
  const float* si_bt = (const float*)d_in[20];
  const float* si_m  = (const float*)d_in[21];
  const float* si_v  = (const float*)d_in[22];
  const float* si_w2 = (const float*)d_in[23];
  const float* si_b2 = (const float*)d_in[24];
  const float* pe_w1 = (const float*)d_in[25];
  const float* pe_w2 = (const float*)d_in[26];
  float* out = (float*)d_out;

  char* p = (char*)d_ws;
  auto alloc = [&](size_t bytes)->char*{
    char* r = p; p += (bytes + 255) & ~(size_t)255; return r;
  };
  ushort* q_bf    = (ushort*)alloc((size_t)4096*512*2);
  ushort* k_bf    = (ushort*)alloc((size_t)4096*512*2);
  ushort* vTb     = (ushort*)alloc((size_t)512*4096*2);
  ushort* att_bf  = (ushort*)alloc((size_t)4096*512*2);
  ushort* conv_x  = (ushort*)alloc((size_t)512*4096*2);
  ushort* conv_nd = (ushort*)alloc((size_t)4096*512*2);
  ushort* Woutb   = (ushort*)alloc((size_t)32768*2);
  ushort* si_w1b  = (ushort*)alloc((size_t)16384*2);
  float*  embed   = (float*) alloc((size_t)64*4096*4);
  float*  lsum_p  = (float*) alloc((size_t)4*8*4096*4);
  float*  pooled  = (float*) alloc(512*4);
  float*  sig_sm  = (float*) alloc(4096*4);
  float*  sig_cm  = (float*) alloc(512*4);
  size_t used = (size_t)(p - (char*)d_ws);
  size_t segBytes = (size_t)4096*512*4 + 256;
  size_t avail = (ws_size > used) ? (ws_size - used) : 0;
  int log2S = 2;
  if (avail < 4*segBytes) log2S = 1;
  if (avail < 2*segBytes) log2S = 0;
  int S = 1 << log2S;
  float* O_part = (float*)alloc((size_t)S*segBytes);

  k_wprep<<<192, 256, 0, stream>>>(Wout, si_w1, Woutb, si_w1b);
  k_qkv<<<dim3(256,3), 256, 0, stream>>>(x_in, Wq, Wk, Wv, scale, q_bf, k_bf, vTb);
  k_attn<<<16*8*S, 256, 0, stream>>>(q_bf, k_bf, vTb, O_part, lsum_p, log2S);
  hipMemsetAsync(pooled, 0, 512*4, stream);
  k_comb<<<256, 256, 0, stream>>>(O_part, lsum_p, att_bf, pooled, S);
  k_conv<<<512, 256, 0, stream>>>(vTb, dw_w, dw_b, dw_g, dw_bt, dw_m, dw_v, conv_x);
  k_tr<<<512, 256, 0, stream>>>(conv_x, conv_nd);
  k_sc<<<257, 256, 0, stream>>>(conv_nd, si_w1b, si_b1, si_g, si_bt, si_m, si_v,
                                si_w2, si_b2, sig_sm,
                                pooled, ci_w1, ci_b1, ci_w2, ci_b2, sig_cm);
  k_pe<<<256, 256, 0, stream>>>(x_in, pe_w1, pe_w2, embed);
  k_final<<<256, 256, 0, stream>>>(att_bf, conv_nd, sig_sm, sig_cm, Woutb, bout, embed, out);
}

// Round 6
// 166.971 us; speedup vs baseline: 1.0723x; 1.0723x over previous
//
#include <hip/hip_runtime.h>

// MultiAttention fused pipeline for MI355X (gfx950).
// B=1, C=64, H=W=64 (N=4096), NH=8, DK=64, D=512.

#define LOG2E 1.442695040888963f

typedef __attribute__((ext_vector_type(8))) short bf16x8;
typedef __attribute__((ext_vector_type(4))) float f32x4;
typedef __attribute__((ext_vector_type(2))) float f32x2;
typedef __attribute__((ext_vector_type(4))) int i32x4;
typedef __attribute__((ext_vector_type(2))) int i32x2;
typedef __attribute__((ext_vector_type(4))) ushort u16x4;

__device__ __forceinline__ ushort f2bf(float x){
  uint u = __float_as_uint(x);
  u += 0x7fffu + ((u >> 16) & 1u);   // round-to-nearest-even
  return (ushort)(u >> 16);
}
__device__ __forceinline__ float bf2f(ushort h){
  return __uint_as_float(((uint)h) << 16);
}
__device__ __forceinline__ float gelu_(float x){
  return 0.5f * x * (1.0f + erff(x * 0.70710678118654752f));
}
__device__ __forceinline__ float sigmoid_(float x){
  return 1.0f / (1.0f + __expf(-x));
}
__device__ __forceinline__ float exp2_(float x){
  float r; asm("v_exp_f32 %0, %1" : "=v"(r) : "v"(x)); return r;
}
__device__ __forceinline__ int cvtpk(float lo, float hi){
  int r; asm("v_cvt_pk_bf16_f32 %0, %1, %2" : "=v"(r) : "v"(lo), "v"(hi)); return r;
}
__device__ __forceinline__ bf16x8 packf8(const float* s){
  f32x4 x0 = *(const f32x4*)s;
  f32x4 x1 = *(const f32x4*)(s+4);
  union{ i32x4 i; bf16x8 v; } u;
  u.i[0]=cvtpk(x0[0],x0[1]); u.i[1]=cvtpk(x0[2],x0[3]);
  u.i[2]=cvtpk(x1[0],x1[1]); u.i[3]=cvtpk(x1[2],x1[3]);
  return u.v;
}

// ---------------- K2: QKV projection + cosine norm; z=3: pe-branch + wprep -
// grid (256, 4): z = 0:q 1:k 2:v 3:(positional-embed conv + weight prep).
__global__ __launch_bounds__(256) void k_qkv(const float* __restrict__ xin,
    const float* __restrict__ Wq, const float* __restrict__ Wk,
    const float* __restrict__ Wv, const float* __restrict__ scale,
    ushort* __restrict__ q_bf, ushort* __restrict__ k_bf, ushort* __restrict__ vT,
    const float* __restrict__ pe_w1, const float* __restrict__ pe_w2,
    float* __restrict__ embed, const float* __restrict__ Wout,
    const float* __restrict__ si_w1, ushort* __restrict__ Woutb,
    ushort* __restrict__ si_w1b, float* __restrict__ pooled){
  __shared__ float t0[20*64];
  __shared__ float t1[18*64];
  const int z = blockIdx.y;
  const int tid = threadIdx.x;
  if (z == 3){
    // ---- weight prep slice: 256 blocks x 192 threads == 49152 elems ----
    if (tid < 192){
      int i = blockIdx.x*192 + tid;
      if (i < 32768) Woutb[i] = f2bf(Wout[i]);
      else           si_w1b[i - 32768] = f2bf(si_w1[i - 32768]);
    }
    if (blockIdx.x == 0){ pooled[tid] = 0.f; pooled[tid+256] = 0.f; }
    // ---- positional embed: dw3x3 -> gelu -> dw3x3, 16-row strip ----
    const int c = blockIdx.x >> 2;
    const int r0 = (blockIdx.x & 3) * 16;
    const float* src = xin + (size_t)c*4096;
#pragma unroll
    for (int i=0;i<5;i++){
      int idx = tid + 256*i;
      if (idx < 1280){
        int lr = idx >> 6, x = idx & 63;
        int gr = r0 - 2 + lr;
        t0[idx] = (gr >= 0 && gr < 64) ? src[gr*64 + x] : 0.f;
      }
    }
    __syncthreads();
    float w1[9], w2[9];
#pragma unroll
    for (int i=0;i<9;i++){ w1[i] = pe_w1[c*9+i]; w2[i] = pe_w2[c*9+i]; }
#pragma unroll
    for (int i=0;i<5;i++){
      int idx = tid + 256*i;
      if (idx < 1152){
        int lr = idx >> 6, x = idx & 63;
        int gr = r0 - 1 + lr;
        float acc = 0.f;
        if (gr >= 0 && gr < 64){
#pragma unroll
          for (int ky=0;ky<3;ky++){
            int gy = gr + ky - 1;
            if (gy < 0 || gy > 63) continue;
#pragma unroll
            for (int kx=0;kx<3;kx++){
              int xx = x + kx - 1;
              if (xx < 0 || xx > 63) continue;
              acc += w1[ky*3+kx] * t0[(lr + ky)*64 + xx];
            }
          }
          acc = gelu_(acc);
        }
        t1[idx] = acc;
      }
    }
    __syncthreads();
    float* dst = embed + (size_t)c*4096;
#pragma unroll
    for (int i=0;i<4;i++){
      int idx = tid + 256*i;
      int lr = idx >> 6, x = idx & 63;
      int gr = r0 + lr;
      float acc = 0.f;
#pragma unroll
      for (int ky=0;ky<3;ky++){
        int gy = gr + ky - 1;
        if (gy < 0 || gy > 63) continue;
#pragma unroll
        for (int kx=0;kx<3;kx++){
          int xx = x + kx - 1;
          if (xx < 0 || xx > 63) continue;
          acc += w2[ky*3+kx] * t1[(lr + ky)*64 + xx];
        }
      }
      dst[gr*64 + x] = acc;
    }
    return;
  }
  const int n0 = blockIdx.x * 16;
  const int lane = tid & 63, w = tid >> 6;
  const int l15 = lane & 15, g = lane >> 4;
  const int obase = w * 128;
  const float* W = (z==0) ? Wq : (z==1) ? Wk : Wv;
  const int n = n0 + l15;
  float xa[8], xc[8];
#pragma unroll
  for (int j=0;j<8;j++){
    xa[j] = xin[(8*g + j)*4096 + n];
    xc[j] = xin[(32 + 8*g + j)*4096 + n];
  }
  union{ i32x4 i; bf16x8 v; } ua, uc;
  ua.i[0]=cvtpk(xa[0],xa[1]); ua.i[1]=cvtpk(xa[2],xa[3]);
  ua.i[2]=cvtpk(xa[4],xa[5]); ua.i[3]=cvtpk(xa[6],xa[7]);
  uc.i[0]=cvtpk(xc[0],xc[1]); uc.i[1]=cvtpk(xc[2],xc[3]);
  uc.i[2]=cvtpk(xc[4],xc[5]); uc.i[3]=cvtpk(xc[6],xc[7]);
  bf16x8 a0 = ua.v, a1 = uc.v;
  f32x4 acc[8];
#pragma unroll
  for (int t=0;t<8;t++) acc[t] = (f32x4){0.f,0.f,0.f,0.f};
#pragma unroll
  for (int t=0;t<8;t++){
    const float* brow = W + (size_t)(obase + 16*t + l15)*64;
    bf16x8 b0 = packf8(brow + 8*g);
    bf16x8 b1 = packf8(brow + 32 + 8*g);
    acc[t] = __builtin_amdgcn_mfma_f32_16x16x32_bf16(a0, b0, acc[t], 0,0,0);
    acc[t] = __builtin_amdgcn_mfma_f32_16x16x32_bf16(a1, b1, acc[t], 0,0,0);
  }
  if (z < 2){
#pragma unroll
    for (int hh=0; hh<2; hh++){
      float sfac = (z==0) ? (scale[2*w+hh] * LOG2E) : 1.0f;
#pragma unroll
      for (int r=0;r<4;r++){
        float ss = 0.f;
#pragma unroll
        for (int tt=0;tt<4;tt++){ float v = acc[hh*4+tt][r]; ss += v*v; }
        ss += __shfl_xor(ss, 1); ss += __shfl_xor(ss, 2);
        ss += __shfl_xor(ss, 4); ss += __shfl_xor(ss, 8);
        float inv = sfac / fmaxf(sqrtf(ss), 1e-12f);
#pragma unroll
        for (int tt=0;tt<4;tt++) acc[hh*4+tt][r] *= inv;
      }
    }
    ushort* dst = (z==0) ? q_bf : k_bf;
#pragma unroll
    for (int t=0;t<8;t++){
      int col = obase + 16*t + l15;
#pragma unroll
      for (int r=0;r<4;r++)
        dst[(size_t)(n0 + 4*g + r)*512 + col] = f2bf(acc[t][r]);
    }
  } else {
#pragma unroll
    for (int t=0;t<8;t++){
      int col = obase + 16*t + l15;
      u16x4 vs;
#pragma unroll
      for (int r=0;r<4;r++) vs[r] = f2bf(acc[t][r]);
      *(u16x4*)(vT + (size_t)col*4096 + n0 + 4*g) = vs;
    }
  }
}

// ---------------- K3: flash attention, 2-deep pipelined LDS staging --------
// block = 256 thr (4 waves), each wave 64 q-rows -> block covers 256 q.
// Pipeline: at iter t write tile t+1 (loaded at t-1) to LDS, issue loads for
// t+2, compute tile t. vmcnt wait ~0: one full iter of latency slack.
__global__ __launch_bounds__(256) void k_attn(const ushort* __restrict__ q_bf,
    const ushort* __restrict__ k_bf, const ushort* __restrict__ vT,
    ushort* __restrict__ O_part, float* __restrict__ lsum_part, int log2S){
  __shared__ ushort Kt[2][4096];
  __shared__ ushort Vt[2][4096];
  const int S = 1 << log2S;
  const int lin = blockIdx.x;
  const int combo = lin & (8*S - 1);
  const int qb = lin >> (3 + log2S);
  const int h = combo >> log2S;
  const int seg = combo & (S - 1);
  const int kv0 = seg * (4096 >> log2S);
  const int iters = (4096 >> log2S) >> 6;
  const int tid = threadIdx.x;
  const int lane = tid & 63, w = tid >> 6;
  const int l15 = lane & 15, g = lane >> 4;

  // staging: thread -> (row = 16*wave + l, 16-col chunk cb); 32B each of K,V
  const int sl = tid & 15, scb = (tid >> 4) & 3;
  const int srow = (tid >> 6)*16 + sl;
  const ushort* gK = k_bf + (size_t)(kv0 + srow)*512 + h*64 + scb*16;
  const ushort* gV = vT + (size_t)(h*64 + srow)*4096 + kv0 + scb*16;
  const int wO0 = srow*64 + (((2*scb)   ^ (srow & 7)) << 3);
  const int wO1 = srow*64 + (((2*scb+1) ^ (srow & 7)) << 3);

  // Q fragments: 64 rows per wave (4 tiles of 16)
  const int qrow0 = qb*256 + w*64;
  bf16x8 qa[4][2];
#pragma unroll
  for (int tq=0;tq<4;tq++){
    const ushort* qrow = q_bf + (size_t)(qrow0 + tq*16 + l15)*512 + h*64;
    qa[tq][0] = *(const bf16x8*)(qrow + 8*g);
    qa[tq][1] = *(const bf16x8*)(qrow + 32 + 8*g);
  }
  f32x4 O[4][4];
#pragma unroll
  for (int tq=0;tq<4;tq++)
#pragma unroll
    for (int t=0;t<4;t++) O[tq][t] = (f32x4){0.f,0.f,0.f,0.f};
  float lsum[4] = {0.f,0.f,0.f,0.f};

  // prologue: tile0 -> LDS[0]; tile1 -> regs
  i32x4 rk0 = *(const i32x4*)gK, rk1 = *(const i32x4*)(gK+8);
  i32x4 rv0 = *(const i32x4*)gV, rv1 = *(const i32x4*)(gV+8);
  *(i32x4*)&Kt[0][wO0] = rk0; *(i32x4*)&Kt[0][wO1] = rk1;
  *(i32x4*)&Vt[0][wO0] = rv0; *(i32x4*)&Vt[0][wO1] = rv1;
  if (iters > 1){
    gK += 64*512; gV += 64;
    rk0 = *(const i32x4*)gK; rk1 = *(const i32x4*)(gK+8);
    rv0 = *(const i32x4*)gV; rv1 = *(const i32x4*)(gV+8);
  }
  __syncthreads();

  const int x7 = l15 & 7;
  const int g2 = g >> 1, gh = (g & 1) << 2;

  for (int it = 0; it < iters; ++it){
    const int buf = it & 1;
    // write tile it+1 (already in regs, loaded a full iter ago)
    if (it + 1 < iters){
      ushort* Kn = Kt[buf^1]; ushort* Vn = Vt[buf^1];
      *(i32x4*)&Kn[wO0] = rk0; *(i32x4*)&Kn[wO1] = rk1;
      *(i32x4*)&Vn[wO0] = rv0; *(i32x4*)&Vn[wO1] = rv1;
      if (it + 2 < iters){
        gK += 64*512; gV += 64;
        rk0 = *(const i32x4*)gK; rk1 = *(const i32x4*)(gK+8);
        rv0 = *(const i32x4*)gV; rv1 = *(const i32x4*)(gV+8);
      }
    }
    const ushort* Kb = Kt[buf];
    const ushort* Vb = Vt[buf];
    // QK^T (S^T: row=key, col=q) -> exp2 -> pack PV A-frags in-register
    i32x4 PA[4][2];
#pragma unroll
    for (int s=0;s<4;s++){
      const int rr = 16*s + l15;
      bf16x8 kf0 = *(const bf16x8*)&Kb[rr*64 + ((g     ^ x7) << 3)];
      bf16x8 kf1 = *(const bf16x8*)&Kb[rr*64 + (((4+g) ^ x7) << 3)];
      const int sp = s >> 1, hi = (s & 1) << 1;
#pragma unroll
      for (int tq=0;tq<4;tq++){
        f32x4 st = (f32x4){0.f,0.f,0.f,0.f};
        st = __builtin_amdgcn_mfma_f32_16x16x32_bf16(kf0, qa[tq][0], st, 0,0,0);
        st = __builtin_amdgcn_mfma_f32_16x16x32_bf16(kf1, qa[tq][1], st, 0,0,0);
        float p0 = exp2_(st[0]), p1 = exp2_(st[1]);
        float p2 = exp2_(st[2]), p3 = exp2_(st[3]);
        lsum[tq] += (p0 + p1) + (p2 + p3);
        PA[tq][sp][hi]   = cvtpk(p0, p1);
        PA[tq][sp][hi+1] = cvtpk(p2, p3);
      }
    }
    // PV
#pragma unroll
    for (int t=0;t<4;t++){
      const int rr = 16*t + l15;
      union { bf16x8 v; i32x2 h2[2]; } u0, u1;
      u0.h2[0] = *(const i32x2*)&Vb[rr*64 + ((g2       ^ x7) << 3) + gh];
      u0.h2[1] = *(const i32x2*)&Vb[rr*64 + (((2 + g2) ^ x7) << 3) + gh];
      u1.h2[0] = *(const i32x2*)&Vb[rr*64 + (((4 + g2) ^ x7) << 3) + gh];
      u1.h2[1] = *(const i32x2*)&Vb[rr*64 + (((6 + g2) ^ x7) << 3) + gh];
#pragma unroll
      for (int tq=0;tq<4;tq++){
        union { i32x4 i; bf16x8 v; } a0, a1;
        a0.i = PA[tq][0]; a1.i = PA[tq][1];
        O[tq][t] = __builtin_amdgcn_mfma_f32_16x16x32_bf16(a0.v, u0.v, O[tq][t], 0,0,0);
        O[tq][t] = __builtin_amdgcn_mfma_f32_16x16x32_bf16(a1.v, u1.v, O[tq][t], 0,0,0);
      }
    }
    __syncthreads();
  }
  // partial softmax denominators (sum over g-groups; q = l15 col labeling)
#pragma unroll
  for (int tq=0;tq<4;tq++){
    float ls = lsum[tq];
    ls += __shfl_xor(ls, 16); ls += __shfl_xor(ls, 32);
    if (g == 0)
      lsum_part[((size_t)seg*8 + h)*4096 + qrow0 + tq*16 + l15] = ls;
  }
  ushort* Op = O_part + (size_t)seg*4096*512;
#pragma unroll
  for (int tq=0;tq<4;tq++)
#pragma unroll
    for (int t=0;t<4;t++)
#pragma unroll
      for (int r=0;r<4;r++)
        Op[(size_t)(qrow0 + tq*16 + 4*g + r)*512 + h*64 + 16*t + l15] = f2bf(O[tq][t][r]);
}

// ---------------- K3b: combine kv-split partials -> att_bf + pooled --------
__global__ __launch_bounds__(256) void k_comb(const ushort* __restrict__ O_part,
    const float* __restrict__ lsum_part, ushort* __restrict__ att_bf,
    float* __restrict__ pooled, int S){
  __shared__ float Linv[16][8];
  const int qbase = blockIdx.x * 16;
  const int tid = threadIdx.x;
  if (tid < 128){
    int q = tid >> 3, h = tid & 7;
    float L = 0.f;
    for (int s=0;s<S;s++) L += lsum_part[((size_t)s*8 + h)*4096 + qbase + q];
    Linv[q][h] = 1.0f / L;
  }
  __syncthreads();
  const int d2 = tid*2;
  const int h = d2 >> 6;
  float pool0 = 0.f, pool1 = 0.f;
  for (int q=0;q<16;q++){
    size_t idx = (size_t)(qbase + q)*512 + d2;
    float o0 = 0.f, o1 = 0.f;
    for (int s=0;s<S;s++){
      uint pk = *(const uint*)(O_part + (size_t)s*4096*512 + idx);
      o0 += bf2f((ushort)pk); o1 += bf2f((ushort)(pk >> 16));
    }
    float li = Linv[q][h];
    o0 *= li; o1 *= li;
    uint pk = (uint)f2bf(o0) | ((uint)f2bf(o1) << 16);
    *(uint*)(att_bf + idx) = pk;
    pool0 += o0; pool1 += o1;
  }
  atomicAdd(&pooled[d2], pool0);
  atomicAdd(&pooled[d2+1], pool1);
}

// ---------------- K4: depthwise 3x3 + bias + BN + GELU (bf16 in/out) -------
__global__ __launch_bounds__(256) void k_conv(const ushort* __restrict__ vT,
    const float* __restrict__ dw_w, const float* __restrict__ dw_b,
    const float* __restrict__ dw_g, const float* __restrict__ dw_bt,
    const float* __restrict__ dw_m, const float* __restrict__ dw_v,
    ushort* __restrict__ conv_x){
  __shared__ float tile[4096];
  const int d = blockIdx.x;
  const int tid = threadIdx.x;
  const ushort* src = vT + (size_t)d*4096;
  {
    bf16x8 a = *(const bf16x8*)(src + tid*16);
    bf16x8 b = *(const bf16x8*)(src + tid*16 + 8);
#pragma unroll
    for (int j=0;j<8;j++){
      tile[tid*16 + j]     = bf2f((ushort)a[j]);
      tile[tid*16 + 8 + j] = bf2f((ushort)b[j]);
    }
  }
  __syncthreads();
  float wv[9];
#pragma unroll
  for (int i=0;i<9;i++) wv[i] = dw_w[d*9+i];
  const float bias = dw_b[d];
  const float bnsc = dw_g[d] * rsqrtf(dw_v[d] + 1e-5f);
  const float bnb  = dw_bt[d] - dw_m[d]*bnsc;
  ushort* dst = conv_x + (size_t)d*4096;
#pragma unroll 4
  for (int i=0;i<16;i++){
    int p = tid + 256*i;
    int y = p >> 6, x = p & 63;
    float acc = 0.f;
#pragma unroll
    for (int ky=0;ky<3;ky++){
      int yy = y + ky - 1;
      if (yy < 0 || yy > 63) continue;
#pragma unroll
      for (int kx=0;kx<3;kx++){
        int xx = x + kx - 1;
        if (xx < 0 || xx > 63) continue;
        acc += wv[ky*3+kx] * tile[yy*64 + xx];
      }
    }
    float cc = (acc + bias)*bnsc + bnb;
    dst[p] = f2bf(gelu_(cc));
  }
}

// ---------------- K4b: transpose conv_x [512][4096] -> conv_nd [4096][512] -
__global__ __launch_bounds__(256) void k_tr(const ushort* __restrict__ src,
    ushort* __restrict__ dst){
  __shared__ ushort tl[64*72];
  const int tid = threadIdx.x;
  const int n0 = (blockIdx.x & 63) * 64;
  const int d0 = (blockIdx.x >> 6) * 64;
  {
    const int r = tid & 63, ch = tid >> 6;   // r = d-row, ch = n-chunk
    union{ i32x4 q[2]; ushort e[16]; } u;
    const ushort* s = src + (size_t)(d0 + r)*4096 + n0 + ch*16;
    u.q[0] = *(const i32x4*)s;
    u.q[1] = *(const i32x4*)(s + 8);
#pragma unroll
    for (int j=0;j<16;j++) tl[(ch*16 + j)*72 + r] = u.e[j];
  }
  __syncthreads();
  {
    const int nr = tid & 63, dc = tid >> 6;
    i32x4 o0 = *(const i32x4*)&tl[nr*72 + dc*16];
    i32x4 o1 = *(const i32x4*)&tl[nr*72 + dc*16 + 8];
    ushort* dp = dst + (size_t)(n0 + nr)*512 + d0 + dc*16;
    *(i32x4*)dp = o0;
    *(i32x4*)(dp + 8) = o1;
  }
}

// ---------------- K5+K6: spatial (K-split MFMA, blocks 0..255) + channel ---
__global__ __launch_bounds__(256) void k_sc(const ushort* __restrict__ conv_nd,
    const ushort* __restrict__ si_w1b, const float* __restrict__ si_b1,
    const float* __restrict__ si_g, const float* __restrict__ si_bt,
    const float* __restrict__ si_m, const float* __restrict__ si_v,
    const float* __restrict__ si_w2, const float* __restrict__ si_b2,
    float* __restrict__ sig_sm,
    const float* __restrict__ pooled, const float* __restrict__ ci_w1,
    const float* __restrict__ ci_b1, const float* __restrict__ ci_w2,
    const float* __restrict__ ci_b2, float* __restrict__ sig_cm){
  const int tid = threadIdx.x;
  if (blockIdx.x == 256){
    __shared__ float pl[512];
    __shared__ float h1[128];
    pl[tid]       = pooled[tid]       * (1.0f/4096.0f);
    pl[tid + 256] = pooled[tid + 256] * (1.0f/4096.0f);
    __syncthreads();
    if (tid < 128){
      float acc = ci_b1[tid];
      const float* wr = ci_w1 + (size_t)tid*512;
#pragma unroll 4
      for (int c=0;c<512;c++) acc += wr[c]*pl[c];
      h1[tid] = gelu_(acc);
    }
    __syncthreads();
#pragma unroll
    for (int dd=0; dd<2; dd++){
      int d = tid + 256*dd;
      float acc = ci_b2[d];
      const float* wr = ci_w2 + (size_t)d*128;
#pragma unroll 4
      for (int e=0;e<128;e++) acc += wr[e]*h1[e];
      sig_cm[d] = sigmoid_(acc);
    }
    return;
  }
  // spatial: 16 n-rows per block, 4 waves split K (128 each), LDS-reduce.
  __shared__ f32x4 part2[4][2][64];
  const int lane = tid & 63, w = tid >> 6;
  const int l15 = lane & 15, g = lane >> 4;
  const int n0 = blockIdx.x * 16;
  const int arow = n0 + l15;
  f32x4 acc[2];
  acc[0] = (f32x4){0.f,0.f,0.f,0.f};
  acc[1] = (f32x4){0.f,0.f,0.f,0.f};
#pragma unroll
  for (int kk=0; kk<4; kk++){
    int k0 = w*128 + kk*32 + 8*g;
    bf16x8 a = *(const bf16x8*)(conv_nd + (size_t)arow*512 + k0);
#pragma unroll
    for (int t=0;t<2;t++){
      bf16x8 b = *(const bf16x8*)(si_w1b + (size_t)(16*t + l15)*512 + k0);
      acc[t] = __builtin_amdgcn_mfma_f32_16x16x32_bf16(a, b, acc[t], 0,0,0);
    }
  }
  part2[w][0][lane] = acc[0];
  part2[w][1][lane] = acc[1];
  __syncthreads();
  if (w == 0){
#pragma unroll
    for (int t=0;t<2;t++){
      f32x4 s4 = part2[0][t][lane];
#pragma unroll
      for (int ww=1;ww<4;ww++) s4 = s4 + part2[ww][t][lane];
      acc[t] = s4;
    }
    float rowv[4] = {0.f,0.f,0.f,0.f};
#pragma unroll
    for (int t=0;t<2;t++){
      int e = 16*t + l15;
      float s = si_g[e] * rsqrtf(si_v[e] + 1e-5f);
      float b1 = si_b1[e] - si_m[e];
      float bt = si_bt[e];
      float w2e = si_w2[e];
#pragma unroll
      for (int r=0;r<4;r++){
        float v = (acc[t][r] + b1)*s + bt;
        rowv[r] += w2e * gelu_(v);
      }
    }
    float sb2 = si_b2[0];
#pragma unroll
    for (int r=0;r<4;r++){
      float v = rowv[r];
      v += __shfl_xor(v,1); v += __shfl_xor(v,2);
      v += __shfl_xor(v,4); v += __shfl_xor(v,8);
      if (l15 == 0)
        sig_sm[n0 + 4*g + r] = sigmoid_(v + sb2);
    }
  }
}

// ---------------- K7: gate fuse + output GEMM (K-split 4 waves) + embed ----
__global__ __launch_bounds__(256) void k_final(const ushort* __restrict__ att_bf,
    const ushort* __restrict__ conv_nd, const float* __restrict__ sig_sm,
    const float* __restrict__ sig_cm, const ushort* __restrict__ Woutb,
    const float* __restrict__ bout, const float* __restrict__ embed,
    float* __restrict__ out){
  __shared__ f32x4 part[4][4][64];
  const int tid = threadIdx.x;
  const int lane = tid & 63, w = tid >> 6;
  const int l15 = lane & 15, g = lane >> 4;
  const int n0 = blockIdx.x * 16;
  const int rowA = n0 + l15;
  const float srow = sig_sm[rowA];
  f32x4 acc[4];
#pragma unroll
  for (int t=0;t<4;t++) acc[t] = (f32x4){0.f,0.f,0.f,0.f};
#pragma unroll
  for (int kk=0;kk<4;kk++){
    int k0 = w*128 + kk*32 + 8*g;
    bf16x8 at8 = *(const bf16x8*)(att_bf + (size_t)rowA*512 + k0);
    bf16x8 cn8 = *(const bf16x8*)(conv_nd + (size_t)rowA*512 + k0);
    bf16x8 af;
#pragma unroll
    for (int i=0;i<8;i++){
      int d = k0 + i;
      float zv = bf2f((ushort)at8[i]) * srow + bf2f((ushort)cn8[i]) * sig_cm[d];
      af[i] = (short)f2bf(zv);
    }
#pragma unroll
    for (int t=0;t<4;t++){
      bf16x8 bf8 = *(const bf16x8*)(Woutb + (size_t)(16*t+l15)*512 + k0);
      acc[t] = __builtin_amdgcn_mfma_f32_16x16x32_bf16(af, bf8, acc[t], 0,0,0);
    }
  }
#pragma unroll
  for (int t=0;t<4;t++) part[w][t][lane] = acc[t];
  __syncthreads();
  // wave w reduces output-column tile t=w: o = 16*w + l15
  {
    f32x4 s4 = part[0][w][lane];
#pragma unroll
    for (int ww=1;ww<4;ww++) s4 = s4 + part[ww][w][lane];
    int o = 16*w + l15;
    float bo = bout[o];
#pragma unroll
    for (int r=0;r<4;r++){
      int row = n0 + 4*g + r;
      size_t idx = (size_t)row*64 + o;
      out[idx] = s4[r] + bo + embed[idx];
    }
  }
}

extern "C" void kernel_launch(void* const* d_in, const int* in_sizes, int n_in,
                              void* d_out, int out_size, void* d_ws, size_t ws_size,
                              hipStream_t stream){
  (void)in_sizes; (void)n_in; (void)out_size;
  const float* x_in  = (const float*)d_in[0];
  const float* Wq    = (const float*)d_in[1];
  const float* Wk    = (const float*)d_in[2];
  const float* Wv    = (const float*)d_in[3];
  const float* scale = (const float*)d_in[4];
  const float* Wout  = (const float*)d_in[5];
  const float* bout  = (const float*)d_in[6];
  const float* dw_w  = (const float*)d_in[7];
  const float* dw_b  = (const float*)d_in[8];
  const float* dw_g  = (const float*)d_in[9];
  const float* dw_bt = (const float*)d_in[10];
  const float* dw_m  = (const float*)d_in[11];
  const float* dw_v  = (const float*)d_in[12];
  const float* ci_w1 = (const float*)d_in[13];
  const float* ci_b1 = (const float*)d_in[14];
  const float* ci_w2 = (const float*)d_in[15];
  const float* ci_b2 = (const float*)d_in[16];
  const float* si_w1 = (const float*)d_in[17];
  const float* si_b1 = (const float*)d_in[18];
  const float* si_g  = (const float*)d_in[19];
  const float* si_bt = (const float*)d_in[20];
  const float* si_m  = (const float*)d_in[21];
  const float* si_v  = (const float*)d_in[22];
  const float* si_w2 = (const float*)d_in[23];
  const float* si_b2 = (const float*)d_in[24];
  const float* pe_w1 = (const float*)d_in[25];
  const float* pe_w2 = (const float*)d_in[26];
  float* out = (float*)d_out;

  char* p = (char*)d_ws;
  auto alloc = [&](size_t bytes)->char*{
    char* r = p; p += (bytes + 255) & ~(size_t)255; return r;
  };
  ushort* q_bf    = (ushort*)alloc((size_t)4096*512*2);
  ushort* k_bf    = (ushort*)alloc((size_t)4096*512*2);
  ushort* vTb     = (ushort*)alloc((size_t)512*4096*2);
  ushort* att_bf  = (ushort*)alloc((size_t)4096*512*2);
  ushort* conv_x  = (ushort*)alloc((size_t)512*4096*2);
  ushort* conv_nd = (ushort*)alloc((size_t)4096*512*2);
  ushort* Woutb   = (ushort*)alloc((size_t)32768*2);
  ushort* si_w1b  = (ushort*)alloc((size_t)16384*2);
  float*  embed   = (float*) alloc((size_t)64*4096*4);
  float*  lsum_p  = (float*) alloc((size_t)4*8*4096*4);
  float*  pooled  = (float*) alloc(512*4);
  float*  sig_sm  = (float*) alloc(4096*4);
  float*  sig_cm  = (float*) alloc(512*4);
  size_t used = (size_t)(p - (char*)d_ws);
  size_t segBytes = (size_t)4096*512*2 + 256;   // bf16 partials
  size_t avail = (ws_size > used) ? (ws_size - used) : 0;
  int log2S = 2;
  if (avail < 4*segBytes) log2S = 1;
  if (avail < 2*segBytes) log2S = 0;
  int S = 1 << log2S;
  ushort* O_part = (ushort*)alloc((size_t)S*segBytes);

  k_qkv<<<dim3(256,4), 256, 0, stream>>>(x_in, Wq, Wk, Wv, scale, q_bf, k_bf, vTb,
                                         pe_w1, pe_w2, embed, Wout, si_w1,
                                         Woutb, si_w1b, pooled);
  k_attn<<<16*8*S, 256, 0, stream>>>(q_bf, k_bf, vTb, O_part, lsum_p, log2S);
  k_comb<<<256, 256, 0, stream>>>(O_part, lsum_p, att_bf, pooled, S);
  k_conv<<<512, 256, 0, stream>>>(vTb, dw_w, dw_b, dw_g, dw_bt, dw_m, dw_v, conv_x);
  k_tr<<<512, 256, 0, stream>>>(conv_x, conv_nd);
  k_sc<<<257, 256, 0, stream>>>(conv_nd, si_w1b, si_b1, si_g, si_bt, si_m, si_v,
                                si_w2, si_b2, sig_sm,
                                pooled, ci_w1, ci_b1, ci_w2, ci_b2, sig_cm);
  k_final<<<256, 256, 0, stream>>>(att_bf, conv_nd, sig_sm, sig_cm, Woutb, bout, embed, out);
}

// Round 7
// 158.343 us; speedup vs baseline: 1.1307x; 1.0545x over previous
//
#include <hip/hip_runtime.h>

// MultiAttention fused pipeline for MI355X (gfx950).
// B=1, C=64, H=W=64 (N=4096), NH=8, DK=64, D=512.

#define LOG2E 1.442695040888963f

typedef __attribute__((ext_vector_type(8))) short bf16x8;
typedef __attribute__((ext_vector_type(4))) float f32x4;
typedef __attribute__((ext_vector_type(4))) int i32x4;
typedef __attribute__((ext_vector_type(2))) int i32x2;
typedef __attribute__((ext_vector_type(4))) ushort u16x4;

__device__ __forceinline__ ushort f2bf(float x){
  uint u = __float_as_uint(x);
  u += 0x7fffu + ((u >> 16) & 1u);   // round-to-nearest-even
  return (ushort)(u >> 16);
}
__device__ __forceinline__ float bf2f(ushort h){
  return __uint_as_float(((uint)h) << 16);
}
__device__ __forceinline__ float gelu_(float x){
  return 0.5f * x * (1.0f + erff(x * 0.70710678118654752f));
}
__device__ __forceinline__ float sigmoid_(float x){
  return 1.0f / (1.0f + __expf(-x));
}
__device__ __forceinline__ float exp2_(float x){
  float r; asm("v_exp_f32 %0, %1" : "=v"(r) : "v"(x)); return r;
}
__device__ __forceinline__ int cvtpk(float lo, float hi){
  int r; asm("v_cvt_pk_bf16_f32 %0, %1, %2" : "=v"(r) : "v"(lo), "v"(hi)); return r;
}
__device__ __forceinline__ bf16x8 packf8(const float* s){
  f32x4 x0 = *(const f32x4*)s;
  f32x4 x1 = *(const f32x4*)(s+4);
  union{ i32x4 i; bf16x8 v; } u;
  u.i[0]=cvtpk(x0[0],x0[1]); u.i[1]=cvtpk(x0[2],x0[3]);
  u.i[2]=cvtpk(x1[0],x1[1]); u.i[3]=cvtpk(x1[2],x1[3]);
  return u.v;
}

// ---------------- K2: QKV projection + cosine norm; z=3: pe-branch + wprep -
__global__ __launch_bounds__(256) void k_qkv(const float* __restrict__ xin,
    const float* __restrict__ Wq, const float* __restrict__ Wk,
    const float* __restrict__ Wv, const float* __restrict__ scale,
    ushort* __restrict__ q_bf, ushort* __restrict__ k_bf, ushort* __restrict__ vT,
    const float* __restrict__ pe_w1, const float* __restrict__ pe_w2,
    float* __restrict__ embed, const float* __restrict__ Wout,
    const float* __restrict__ si_w1, ushort* __restrict__ Woutb,
    ushort* __restrict__ si_w1b, float* __restrict__ pooled){
  __shared__ float t0[20*64];
  __shared__ float t1[18*64];
  const int z = blockIdx.y;
  const int tid = threadIdx.x;
  if (z == 3){
    if (tid < 192){
      int i = blockIdx.x*192 + tid;
      if (i < 32768) Woutb[i] = f2bf(Wout[i]);
      else           si_w1b[i - 32768] = f2bf(si_w1[i - 32768]);
    }
    if (blockIdx.x == 0){ pooled[tid] = 0.f; pooled[tid+256] = 0.f; }
    const int c = blockIdx.x >> 2;
    const int r0 = (blockIdx.x & 3) * 16;
    const float* src = xin + (size_t)c*4096;
#pragma unroll
    for (int i=0;i<5;i++){
      int idx = tid + 256*i;
      if (idx < 1280){
        int lr = idx >> 6, x = idx & 63;
        int gr = r0 - 2 + lr;
        t0[idx] = (gr >= 0 && gr < 64) ? src[gr*64 + x] : 0.f;
      }
    }
    __syncthreads();
    float w1[9], w2[9];
#pragma unroll
    for (int i=0;i<9;i++){ w1[i] = pe_w1[c*9+i]; w2[i] = pe_w2[c*9+i]; }
#pragma unroll
    for (int i=0;i<5;i++){
      int idx = tid + 256*i;
      if (idx < 1152){
        int lr = idx >> 6, x = idx & 63;
        int gr = r0 - 1 + lr;
        float acc = 0.f;
        if (gr >= 0 && gr < 64){
#pragma unroll
          for (int ky=0;ky<3;ky++){
            int gy = gr + ky - 1;
            if (gy < 0 || gy > 63) continue;
#pragma unroll
            for (int kx=0;kx<3;kx++){
              int xx = x + kx - 1;
              if (xx < 0 || xx > 63) continue;
              acc += w1[ky*3+kx] * t0[(lr + ky)*64 + xx];
            }
          }
          acc = gelu_(acc);
        }
        t1[idx] = acc;
      }
    }
    __syncthreads();
    float* dst = embed + (size_t)c*4096;
#pragma unroll
    for (int i=0;i<4;i++){
      int idx = tid + 256*i;
      int lr = idx >> 6, x = idx & 63;
      int gr = r0 + lr;
      float acc = 0.f;
#pragma unroll
      for (int ky=0;ky<3;ky++){
        int gy = gr + ky - 1;
        if (gy < 0 || gy > 63) continue;
#pragma unroll
        for (int kx=0;kx<3;kx++){
          int xx = x + kx - 1;
          if (xx < 0 || xx > 63) continue;
          acc += w2[ky*3+kx] * t1[(lr + ky)*64 + xx];
        }
      }
      dst[gr*64 + x] = acc;
    }
    return;
  }
  const int n0 = blockIdx.x * 16;
  const int lane = tid & 63, w = tid >> 6;
  const int l15 = lane & 15, g = lane >> 4;
  const int obase = w * 128;
  const float* W = (z==0) ? Wq : (z==1) ? Wk : Wv;
  const int n = n0 + l15;
  float xa[8], xc[8];
#pragma unroll
  for (int j=0;j<8;j++){
    xa[j] = xin[(8*g + j)*4096 + n];
    xc[j] = xin[(32 + 8*g + j)*4096 + n];
  }
  union{ i32x4 i; bf16x8 v; } ua, uc;
  ua.i[0]=cvtpk(xa[0],xa[1]); ua.i[1]=cvtpk(xa[2],xa[3]);
  ua.i[2]=cvtpk(xa[4],xa[5]); ua.i[3]=cvtpk(xa[6],xa[7]);
  uc.i[0]=cvtpk(xc[0],xc[1]); uc.i[1]=cvtpk(xc[2],xc[3]);
  uc.i[2]=cvtpk(xc[4],xc[5]); uc.i[3]=cvtpk(xc[6],xc[7]);
  bf16x8 a0 = ua.v, a1 = uc.v;
  f32x4 acc[8];
#pragma unroll
  for (int t=0;t<8;t++) acc[t] = (f32x4){0.f,0.f,0.f,0.f};
#pragma unroll
  for (int t=0;t<8;t++){
    const float* brow = W + (size_t)(obase + 16*t + l15)*64;
    bf16x8 b0 = packf8(brow + 8*g);
    bf16x8 b1 = packf8(brow + 32 + 8*g);
    acc[t] = __builtin_amdgcn_mfma_f32_16x16x32_bf16(a0, b0, acc[t], 0,0,0);
    acc[t] = __builtin_amdgcn_mfma_f32_16x16x32_bf16(a1, b1, acc[t], 0,0,0);
  }
  if (z < 2){
#pragma unroll
    for (int hh=0; hh<2; hh++){
      float sfac = (z==0) ? (scale[2*w+hh] * LOG2E) : 1.0f;
#pragma unroll
      for (int r=0;r<4;r++){
        float ss = 0.f;
#pragma unroll
        for (int tt=0;tt<4;tt++){ float v = acc[hh*4+tt][r]; ss += v*v; }
        ss += __shfl_xor(ss, 1); ss += __shfl_xor(ss, 2);
        ss += __shfl_xor(ss, 4); ss += __shfl_xor(ss, 8);
        float inv = sfac / fmaxf(sqrtf(ss), 1e-12f);
#pragma unroll
        for (int tt=0;tt<4;tt++) acc[hh*4+tt][r] *= inv;
      }
    }
    ushort* dst = (z==0) ? q_bf : k_bf;
#pragma unroll
    for (int t=0;t<8;t++){
      int col = obase + 16*t + l15;
#pragma unroll
      for (int r=0;r<4;r++)
        dst[(size_t)(n0 + 4*g + r)*512 + col] = f2bf(acc[t][r]);
    }
  } else {
#pragma unroll
    for (int t=0;t<8;t++){
      int col = obase + 16*t + l15;
      u16x4 vs;
#pragma unroll
      for (int r=0;r<4;r++) vs[r] = f2bf(acc[t][r]);
      *(u16x4*)(vT + (size_t)col*4096 + n0 + 4*g) = vs;
    }
  }
}

// ---------------- K3: flash attention, KVB=128, 2-deep pipeline, setprio ---
// block = 256 thr (4 waves), each wave 64 q-rows. 8 barriers per block (S=4).
__global__ __launch_bounds__(256) void k_attn(const ushort* __restrict__ q_bf,
    const ushort* __restrict__ k_bf, const ushort* __restrict__ vT,
    ushort* __restrict__ O_part, float* __restrict__ lsum_part, int log2S){
  __shared__ ushort Kt[2][128*64];
  __shared__ ushort Vt[2][64*128];
  const int S = 1 << log2S;
  const int lin = blockIdx.x;
  const int combo = lin & (8*S - 1);
  const int qb = lin >> (3 + log2S);
  const int h = combo >> log2S;
  const int seg = combo & (S - 1);
  const int kv0 = seg * (4096 >> log2S);
  const int iters = (4096 >> log2S) >> 7;
  const int tid = threadIdx.x;
  const int lane = tid & 63, w = tid >> 6;
  const int l15 = lane & 15, g = lane >> 4;

  // staging: 4 chunks of 16B each for K (128x64) and V (64x128)
  const ushort* gKp[4]; const ushort* gVp[4];
  int wK[4], wV[4];
#pragma unroll
  for (int j=0;j<4;j++){
    int c = tid + 256*j;
    int rK = c >> 3, cbK = c & 7;
    gKp[j] = k_bf + (size_t)(kv0 + rK)*512 + h*64 + cbK*8;
    wK[j] = rK*64 + ((cbK ^ (rK & 7)) << 3);
    int rV = c >> 4, cbV = c & 15;
    gVp[j] = vT + (size_t)(h*64 + rV)*4096 + kv0 + cbV*8;
    wV[j] = rV*128 + ((cbV ^ (rV & 7)) << 3);
  }

  const int qrow0 = qb*256 + w*64;
  bf16x8 qa[4][2];
#pragma unroll
  for (int tq=0;tq<4;tq++){
    const ushort* qrow = q_bf + (size_t)(qrow0 + tq*16 + l15)*512 + h*64;
    qa[tq][0] = *(const bf16x8*)(qrow + 8*g);
    qa[tq][1] = *(const bf16x8*)(qrow + 32 + 8*g);
  }
  f32x4 O[4][4];
#pragma unroll
  for (int tq=0;tq<4;tq++)
#pragma unroll
    for (int t=0;t<4;t++) O[tq][t] = (f32x4){0.f,0.f,0.f,0.f};
  float lsum[4] = {0.f,0.f,0.f,0.f};

  // prologue: tile0 -> LDS[0]; tile1 -> regs
  i32x4 rk[4], rv[4];
#pragma unroll
  for (int j=0;j<4;j++){ rk[j] = *(const i32x4*)gKp[j]; rv[j] = *(const i32x4*)gVp[j]; }
#pragma unroll
  for (int j=0;j<4;j++){
    *(i32x4*)&Kt[0][wK[j]] = rk[j];
    *(i32x4*)&Vt[0][wV[j]] = rv[j];
  }
  if (iters > 1){
#pragma unroll
    for (int j=0;j<4;j++){
      gKp[j] += 128*512; gVp[j] += 128;
      rk[j] = *(const i32x4*)gKp[j]; rv[j] = *(const i32x4*)gVp[j];
    }
  }
  __syncthreads();

  const int x7 = l15 & 7;
  const int gh2 = (g & 1) << 2;
  const int gq = g >> 1;

  for (int it = 0; it < iters; ++it){
    const int buf = it & 1;
    if (it + 1 < iters){
      ushort* Kn = Kt[buf^1]; ushort* Vn = Vt[buf^1];
#pragma unroll
      for (int j=0;j<4;j++){
        *(i32x4*)&Kn[wK[j]] = rk[j];
        *(i32x4*)&Vn[wV[j]] = rv[j];
      }
      if (it + 2 < iters){
#pragma unroll
        for (int j=0;j<4;j++){
          gKp[j] += 128*512; gVp[j] += 128;
          rk[j] = *(const i32x4*)gKp[j]; rv[j] = *(const i32x4*)gVp[j];
        }
      }
    }
    const ushort* Kb = Kt[buf];
    const ushort* Vb = Vt[buf];
#pragma unroll
    for (int ks=0; ks<4; ++ks){
      i32x4 PA[4];
#pragma unroll
      for (int s2=0; s2<2; ++s2){
        const int rr = 16*(2*ks + s2) + l15;
        bf16x8 kf0 = *(const bf16x8*)&Kb[rr*64 + ((g     ^ x7) << 3)];
        bf16x8 kf1 = *(const bf16x8*)&Kb[rr*64 + (((4+g) ^ x7) << 3)];
#pragma unroll
        for (int tq=0; tq<4; ++tq){
          f32x4 st = (f32x4){0.f,0.f,0.f,0.f};
          st = __builtin_amdgcn_mfma_f32_16x16x32_bf16(kf0, qa[tq][0], st, 0,0,0);
          st = __builtin_amdgcn_mfma_f32_16x16x32_bf16(kf1, qa[tq][1], st, 0,0,0);
          float p0 = exp2_(st[0]), p1 = exp2_(st[1]);
          float p2 = exp2_(st[2]), p3 = exp2_(st[3]);
          lsum[tq] += (p0 + p1) + (p2 + p3);
          PA[tq][2*s2]   = cvtpk(p0, p1);
          PA[tq][2*s2+1] = cvtpk(p2, p3);
        }
      }
      __builtin_amdgcn_s_setprio(1);
#pragma unroll
      for (int t=0;t<4;++t){
        const int rr = 16*t + l15;
        const int c0 = 4*ks + gq, c1 = 4*ks + 2 + gq;
        union { bf16x8 v; i32x2 h2[2]; } u;
        u.h2[0] = *(const i32x2*)&Vb[rr*128 + ((c0 ^ x7) << 3) + gh2];
        u.h2[1] = *(const i32x2*)&Vb[rr*128 + ((c1 ^ x7) << 3) + gh2];
#pragma unroll
        for (int tq=0;tq<4;++tq){
          union { i32x4 i; bf16x8 v; } a; a.i = PA[tq];
          O[tq][t] = __builtin_amdgcn_mfma_f32_16x16x32_bf16(a.v, u.v, O[tq][t], 0,0,0);
        }
      }
      __builtin_amdgcn_s_setprio(0);
    }
    __syncthreads();
  }
#pragma unroll
  for (int tq=0;tq<4;tq++){
    float ls = lsum[tq];
    ls += __shfl_xor(ls, 16); ls += __shfl_xor(ls, 32);
    if (g == 0)
      lsum_part[((size_t)seg*8 + h)*4096 + qrow0 + tq*16 + l15] = ls;
  }
  ushort* Op = O_part + (size_t)seg*4096*512;
#pragma unroll
  for (int tq=0;tq<4;tq++)
#pragma unroll
    for (int t=0;t<4;t++)
#pragma unroll
      for (int r=0;r<4;r++)
        Op[(size_t)(qrow0 + tq*16 + 4*g + r)*512 + h*64 + 16*t + l15] = f2bf(O[tq][t][r]);
}

// ---------------- K3b: combine kv-split partials -> att_bf + pooled --------
__global__ __launch_bounds__(256) void k_comb(const ushort* __restrict__ O_part,
    const float* __restrict__ lsum_part, ushort* __restrict__ att_bf,
    float* __restrict__ pooled, int S){
  __shared__ float Linv[8][8];
  const int qbase = blockIdx.x * 8;
  const int tid = threadIdx.x;
  if (tid < 64){
    int q = tid >> 3, h = tid & 7;
    float L = 0.f;
    for (int s=0;s<S;s++) L += lsum_part[((size_t)s*8 + h)*4096 + qbase + q];
    Linv[q][h] = 1.0f / L;
  }
  __syncthreads();
  const int d2 = tid*2;
  const int h = d2 >> 6;
  float pool0 = 0.f, pool1 = 0.f;
  for (int q=0;q<8;q++){
    size_t idx = (size_t)(qbase + q)*512 + d2;
    float o0 = 0.f, o1 = 0.f;
    for (int s=0;s<S;s++){
      uint pk = *(const uint*)(O_part + (size_t)s*4096*512 + idx);
      o0 += bf2f((ushort)pk); o1 += bf2f((ushort)(pk >> 16));
    }
    float li = Linv[q][h];
    o0 *= li; o1 *= li;
    uint pk = (uint)f2bf(o0) | ((uint)f2bf(o1) << 16);
    *(uint*)(att_bf + idx) = pk;
    pool0 += o0; pool1 += o1;
  }
  atomicAdd(&pooled[d2], pool0);
  atomicAdd(&pooled[d2+1], pool1);
}

// ---------------- K4: depthwise conv (+block 512: channel MLP) -------------
__global__ __launch_bounds__(256) void k_conv(const ushort* __restrict__ vT,
    const float* __restrict__ dw_w, const float* __restrict__ dw_b,
    const float* __restrict__ dw_g, const float* __restrict__ dw_bt,
    const float* __restrict__ dw_m, const float* __restrict__ dw_v,
    ushort* __restrict__ conv_x,
    const float* __restrict__ pooled, const float* __restrict__ ci_w1,
    const float* __restrict__ ci_b1, const float* __restrict__ ci_w2,
    const float* __restrict__ ci_b2, float* __restrict__ sig_cm){
  __shared__ float tile[4096];
  __shared__ float h1[128];
  const int tid = threadIdx.x;
  if (blockIdx.x == 512){
    tile[tid]       = pooled[tid]       * (1.0f/4096.0f);
    tile[tid + 256] = pooled[tid + 256] * (1.0f/4096.0f);
    __syncthreads();
    if (tid < 128){
      float acc = ci_b1[tid];
      const float* wr = ci_w1 + (size_t)tid*512;
#pragma unroll 4
      for (int c=0;c<512;c++) acc += wr[c]*tile[c];
      h1[tid] = gelu_(acc);
    }
    __syncthreads();
#pragma unroll
    for (int dd=0; dd<2; dd++){
      int d = tid + 256*dd;
      float acc = ci_b2[d];
      const float* wr = ci_w2 + (size_t)d*128;
#pragma unroll 4
      for (int e=0;e<128;e++) acc += wr[e]*h1[e];
      sig_cm[d] = sigmoid_(acc);
    }
    return;
  }
  const int d = blockIdx.x;
  const ushort* src = vT + (size_t)d*4096;
  {
    bf16x8 a = *(const bf16x8*)(src + tid*16);
    bf16x8 b = *(const bf16x8*)(src + tid*16 + 8);
#pragma unroll
    for (int j=0;j<8;j++){
      tile[tid*16 + j]     = bf2f((ushort)a[j]);
      tile[tid*16 + 8 + j] = bf2f((ushort)b[j]);
    }
  }
  __syncthreads();
  float wv[9];
#pragma unroll
  for (int i=0;i<9;i++) wv[i] = dw_w[d*9+i];
  const float bias = dw_b[d];
  const float bnsc = dw_g[d] * rsqrtf(dw_v[d] + 1e-5f);
  const float bnb  = dw_bt[d] - dw_m[d]*bnsc;
  ushort* dst = conv_x + (size_t)d*4096;
#pragma unroll 4
  for (int i=0;i<16;i++){
    int p = tid + 256*i;
    int y = p >> 6, x = p & 63;
    float acc = 0.f;
#pragma unroll
    for (int ky=0;ky<3;ky++){
      int yy = y + ky - 1;
      if (yy < 0 || yy > 63) continue;
#pragma unroll
      for (int kx=0;kx<3;kx++){
        int xx = x + kx - 1;
        if (xx < 0 || xx > 63) continue;
        acc += wv[ky*3+kx] * tile[yy*64 + xx];
      }
    }
    float cc = (acc + bias)*bnsc + bnb;
    dst[p] = f2bf(gelu_(cc));
  }
}

// ---------------- K4b: transpose conv_x [512][4096] -> conv_nd [4096][512] -
__global__ __launch_bounds__(256) void k_tr(const ushort* __restrict__ src,
    ushort* __restrict__ dst){
  __shared__ ushort tl[64*72];
  const int tid = threadIdx.x;
  const int n0 = (blockIdx.x & 63) * 64;
  const int d0 = (blockIdx.x >> 6) * 64;
  {
    const int r = tid & 63, ch = tid >> 6;
    union{ i32x4 q[2]; ushort e[16]; } u;
    const ushort* s = src + (size_t)(d0 + r)*4096 + n0 + ch*16;
    u.q[0] = *(const i32x4*)s;
    u.q[1] = *(const i32x4*)(s + 8);
#pragma unroll
    for (int j=0;j<16;j++) tl[(ch*16 + j)*72 + r] = u.e[j];
  }
  __syncthreads();
  {
    const int nr = tid & 63, dc = tid >> 6;
    i32x4 o0 = *(const i32x4*)&tl[nr*72 + dc*16];
    i32x4 o1 = *(const i32x4*)&tl[nr*72 + dc*16 + 8];
    ushort* dp = dst + (size_t)(n0 + nr)*512 + d0 + dc*16;
    *(i32x4*)dp = o0;
    *(i32x4*)(dp + 8) = o1;
  }
}

// ---------------- K7: spatial-SE + gate fuse + output GEMM + embed ---------
// grid 256 x 256thr: 16 n-rows/block; 4 waves split K. Spatial sigmoid
// computed in-block (reuses conv_nd fragments), sig_cm from k_conv blk 512.
__global__ __launch_bounds__(256) void k_final(const ushort* __restrict__ att_bf,
    const ushort* __restrict__ conv_nd, const ushort* __restrict__ si_w1b,
    const float* __restrict__ si_b1, const float* __restrict__ si_g,
    const float* __restrict__ si_bt, const float* __restrict__ si_m,
    const float* __restrict__ si_v, const float* __restrict__ si_w2,
    const float* __restrict__ si_b2, const float* __restrict__ sig_cm,
    const ushort* __restrict__ Woutb, const float* __restrict__ bout,
    const float* __restrict__ embed, float* __restrict__ out){
  __shared__ f32x4 part2[4][2][64];
  __shared__ float smv[16];
  __shared__ f32x4 part[4][4][64];
  const int tid = threadIdx.x;
  const int lane = tid & 63, w = tid >> 6;
  const int l15 = lane & 15, g = lane >> 4;
  const int n0 = blockIdx.x * 16;
  const int rowA = n0 + l15;
  // fragments reused across both phases
  bf16x8 at8[4], cn8[4];
#pragma unroll
  for (int kk=0;kk<4;kk++){
    int k0 = w*128 + kk*32 + 8*g;
    at8[kk] = *(const bf16x8*)(att_bf + (size_t)rowA*512 + k0);
    cn8[kk] = *(const bf16x8*)(conv_nd + (size_t)rowA*512 + k0);
  }
  // phase 1: spatial s1 = conv_nd . si_w1^T (32 e), K-split by wave
  f32x4 a2[2];
  a2[0] = (f32x4){0.f,0.f,0.f,0.f};
  a2[1] = (f32x4){0.f,0.f,0.f,0.f};
#pragma unroll
  for (int kk=0;kk<4;kk++){
    int k0 = w*128 + kk*32 + 8*g;
#pragma unroll
    for (int t=0;t<2;t++){
      bf16x8 b = *(const bf16x8*)(si_w1b + (size_t)(16*t + l15)*512 + k0);
      a2[t] = __builtin_amdgcn_mfma_f32_16x16x32_bf16(cn8[kk], b, a2[t], 0,0,0);
    }
  }
  part2[w][0][lane] = a2[0];
  part2[w][1][lane] = a2[1];
  __syncthreads();
  if (w == 0){
    float rowv[4] = {0.f,0.f,0.f,0.f};
#pragma unroll
    for (int t=0;t<2;t++){
      f32x4 s4 = part2[0][t][lane];
#pragma unroll
      for (int ww=1;ww<4;ww++) s4 = s4 + part2[ww][t][lane];
      int e = 16*t + l15;
      float s = si_g[e] * rsqrtf(si_v[e] + 1e-5f);
      float b1 = si_b1[e] - si_m[e];
      float bt = si_bt[e];
      float w2e = si_w2[e];
#pragma unroll
      for (int r=0;r<4;r++){
        float v = (s4[r] + b1)*s + bt;
        rowv[r] += w2e * gelu_(v);
      }
    }
    float sb2 = si_b2[0];
#pragma unroll
    for (int r=0;r<4;r++){
      float v = rowv[r];
      v += __shfl_xor(v,1); v += __shfl_xor(v,2);
      v += __shfl_xor(v,4); v += __shfl_xor(v,8);
      if (l15 == 0) smv[4*g + r] = sigmoid_(v + sb2);
    }
  }
  __syncthreads();
  const float srow = smv[l15];
  // phase 2: gate + output GEMM
  f32x4 acc[4];
#pragma unroll
  for (int t=0;t<4;t++) acc[t] = (f32x4){0.f,0.f,0.f,0.f};
#pragma unroll
  for (int kk=0;kk<4;kk++){
    int k0 = w*128 + kk*32 + 8*g;
    f32x4 sc0 = *(const f32x4*)(sig_cm + k0);
    f32x4 sc1 = *(const f32x4*)(sig_cm + k0 + 4);
    bf16x8 af;
#pragma unroll
    for (int i=0;i<8;i++){
      float scm = (i < 4) ? sc0[i & 3] : sc1[i & 3];
      float zv = bf2f((ushort)at8[kk][i]) * srow + bf2f((ushort)cn8[kk][i]) * scm;
      af[i] = (short)f2bf(zv);
    }
#pragma unroll
    for (int t=0;t<4;t++){
      bf16x8 bf8 = *(const bf16x8*)(Woutb + (size_t)(16*t+l15)*512 + k0);
      acc[t] = __builtin_amdgcn_mfma_f32_16x16x32_bf16(af, bf8, acc[t], 0,0,0);
    }
  }
#pragma unroll
  for (int t=0;t<4;t++) part[w][t][lane] = acc[t];
  __syncthreads();
  {
    f32x4 s4 = part[0][w][lane];
#pragma unroll
    for (int ww=1;ww<4;ww++) s4 = s4 + part[ww][w][lane];
    int o = 16*w + l15;
    float bo = bout[o];
#pragma unroll
    for (int r=0;r<4;r++){
      int row = n0 + 4*g + r;
      size_t idx = (size_t)row*64 + o;
      out[idx] = s4[r] + bo + embed[idx];
    }
  }
}

extern "C" void kernel_launch(void* const* d_in, const int* in_sizes, int n_in,
                              void* d_out, int out_size, void* d_ws, size_t ws_size,
                              hipStream_t stream){
  (void)in_sizes; (void)n_in; (void)out_size;
  const float* x_in  = (const float*)d_in[0];
  const float* Wq    = (const float*)d_in[1];
  const float* Wk    = (const float*)d_in[2];
  const float* Wv    = (const float*)d_in[3];
  const float* scale = (const float*)d_in[4];
  const float* Wout  = (const float*)d_in[5];
  const float* bout  = (const float*)d_in[6];
  const float* dw_w  = (const float*)d_in[7];
  const float* dw_b  = (const float*)d_in[8];
  const float* dw_g  = (const float*)d_in[9];
  const float* dw_bt = (const float*)d_in[10];
  const float* dw_m  = (const float*)d_in[11];
  const float* dw_v  = (const float*)d_in[12];
  const float* ci_w1 = (const float*)d_in[13];
  const float* ci_b1 = (const float*)d_in[14];
  const float* ci_w2 = (const float*)d_in[15];
  const float* ci_b2 = (const float*)d_in[16];
  const float* si_w1 = (const float*)d_in[17];
  const float* si_b1 = (const float*)d_in[18];
  const float* si_g  = (const float*)d_in[19];
  const float* si_bt = (const float*)d_in[20];
  const float* si_m  = (const float*)d_in[21];
  const float* si_v  = (const float*)d_in[22];
  const float* si_w2 = (const float*)d_in[23];
  const float* si_b2 = (const float*)d_in[24];
  const float* pe_w1 = (const float*)d_in[25];
  const float* pe_w2 = (const float*)d_in[26];
  float* out = (float*)d_out;

  char* p = (char*)d_ws;
  auto alloc = [&](size_t bytes)->char*{
    char* r = p; p += (bytes + 255) & ~(size_t)255; return r;
  };
  ushort* q_bf    = (ushort*)alloc((size_t)4096*512*2);
  ushort* k_bf    = (ushort*)alloc((size_t)4096*512*2);
  ushort* vTb     = (ushort*)alloc((size_t)512*4096*2);
  ushort* att_bf  = (ushort*)alloc((size_t)4096*512*2);
  ushort* conv_x  = (ushort*)alloc((size_t)512*4096*2);
  ushort* conv_nd = (ushort*)alloc((size_t)4096*512*2);
  ushort* Woutb   = (ushort*)alloc((size_t)32768*2);
  ushort* si_w1b  = (ushort*)alloc((size_t)16384*2);
  float*  embed   = (float*) alloc((size_t)64*4096*4);
  float*  lsum_p  = (float*) alloc((size_t)4*8*4096*4);
  float*  pooled  = (float*) alloc(512*4);
  float*  sig_cm  = (float*) alloc(512*4);
  size_t used = (size_t)(p - (char*)d_ws);
  size_t segBytes = (size_t)4096*512*2 + 256;   // bf16 partials
  size_t avail = (ws_size > used) ? (ws_size - used) : 0;
  int log2S = 2;
  if (avail < 4*segBytes) log2S = 1;
  if (avail < 2*segBytes) log2S = 0;
  int S = 1 << log2S;
  ushort* O_part = (ushort*)alloc((size_t)S*segBytes);

  k_qkv<<<dim3(256,4), 256, 0, stream>>>(x_in, Wq, Wk, Wv, scale, q_bf, k_bf, vTb,
                                         pe_w1, pe_w2, embed, Wout, si_w1,
                                         Woutb, si_w1b, pooled);
  k_attn<<<16*8*S, 256, 0, stream>>>(q_bf, k_bf, vTb, O_part, lsum_p, log2S);
  k_comb<<<512, 256, 0, stream>>>(O_part, lsum_p, att_bf, pooled, S);
  k_conv<<<513, 256, 0, stream>>>(vTb, dw_w, dw_b, dw_g, dw_bt, dw_m, dw_v, conv_x,
                                  pooled, ci_w1, ci_b1, ci_w2, ci_b2, sig_cm);
  k_tr<<<512, 256, 0, stream>>>(conv_x, conv_nd);
  k_final<<<256, 256, 0, stream>>>(att_bf, conv_nd, si_w1b, si_b1, si_g, si_bt,
                                   si_m, si_v, si_w2, si_b2, sig_cm,
                                   Woutb, bout, embed, out);
}